// Round 2
// baseline (373.944 us; speedup 1.0000x reference)
//
#include <hip/hip_runtime.h>
#include <hip/hip_bf16.h>
#include <cstdint>
#include <cstddef>

// Problem constants
#define NFIELD 10
#define BATCH  16384
#define NIDS   20
#define DEMB   16
#define NFEAT  160   // NFIELD * DEMB
#define NEXP   8
#define NS     64
#define NG     3
#define NT     32

// fp32 weight region offsets (in floats) inside the weight block
#define EW_OFF 0
#define GW_OFF 81920
#define TW_OFF 85760
#define OW_OFF 91904
#define EB_OFF 92096
#define GB_OFF 92608
#define TB_OFF 92632
#define OB_OFF 92728
#define W_TOTAL 92734

// workspace layout (bytes)
#define X_BYTES   ((size_t)BATCH * NFEAT * 4)          // fp32 x: 10,485,760
#define W_BYTES   ((size_t)W_TOTAL * 4)                //    370,936
#define WF_OFF_B  X_BYTES
#define FLAG_OFF_B (X_BYTES + W_BYTES)                 // 10,856,696 (8-aligned)

__device__ __forceinline__ float bflo(uint32_t u) {
    union { uint32_t u; float f; } c; c.u = u << 16; return c.f;
}
__device__ __forceinline__ float bfhi(uint32_t u) {
    union { uint32_t u; float f; } c; c.u = u & 0xffff0000u; return c.f;
}
__device__ __forceinline__ float bf1(uint16_t v) {
    union { uint32_t u; float f; } c; c.u = ((uint32_t)v) << 16; return c.f;
}
__device__ __forceinline__ uint16_t f2bf(float f) {
    union { float f; uint32_t u; } c; c.f = f;
    uint32_t r = c.u + 0x7fffu + ((c.u >> 16) & 1u);  // RTNE
    return (uint16_t)(r >> 16);
}

// ---------------------------------------------------------------------------
// Kernel S: sniff input dtypes. flags[0]=1 if ids are int64, flags[1]=1 if
// float arrays are bf16. One block, 64 threads (one wave).
// ---------------------------------------------------------------------------
__global__ __launch_bounds__(64) void sniff_dtypes(
    const uint32_t* __restrict__ ids_w,
    const uint32_t* __restrict__ emb_w,
    int* __restrict__ flags)
{
    int t = threadIdx.x;

    // ids: if int64 little-endian with values < 2^31, every high word is 0.
    // sample pair index p: bytes touched <= 8*1,575,000+8 = 12.6 MB, in-bounds
    // under BOTH interpretations (int32: 13.1 MB, int64: 26.2 MB).
    size_t p = (size_t)t * 25000;
    uint32_t hi = ids_w[2 * p + 1];
    int n_hi = __popcll(__ballot(hi != 0));

    // emb: low halfword of each 32-bit word. If data is bf16 pairs drawn from
    // U(-1,1), bits[14:8] (exponent upper bits) fall in [0x3B,0x3F] ~99.6% of
    // the time; if data is fp32, those are random mantissa bits (~3.9% hit).
    // word idx <= 7,875,000 -> 31.5 MB, in-bounds under both (32 MB / 64 MB).
    size_t q = (size_t)t * 125000;
    uint32_t w = emb_w[q];
    uint32_t v = (w >> 8) & 0x7Fu;
    int n_bf = __popcll(__ballot(v >= 0x3Bu && v <= 0x3Fu));

    if (t == 0) {
        flags[0] = (n_hi < 8)   ? 1 : 0;   // ids are int64
        flags[1] = (n_bf >= 32) ? 1 : 0;   // floats are bf16
    }
}

// ---------------------------------------------------------------------------
// Kernel 0: convert all small weights/biases (bf16 or fp32) -> fp32 workspace
// ---------------------------------------------------------------------------
__global__ __launch_bounds__(256) void convert_weights(
    const void* __restrict__ ew, const void* __restrict__ eb,
    const void* __restrict__ gw, const void* __restrict__ gb,
    const void* __restrict__ tw, const void* __restrict__ tb,
    const void* __restrict__ ow, const void* __restrict__ ob,
    float* __restrict__ dst, const int* __restrict__ flags)
{
    int i = blockIdx.x * 256 + threadIdx.x;
    if (i >= W_TOTAL) return;
    const void* p; int off;
    if      (i < GW_OFF) { p = ew; off = i - EW_OFF; }
    else if (i < TW_OFF) { p = gw; off = i - GW_OFF; }
    else if (i < OW_OFF) { p = tw; off = i - TW_OFF; }
    else if (i < EB_OFF) { p = ow; off = i - OW_OFF; }
    else if (i < GB_OFF) { p = eb; off = i - EB_OFF; }
    else if (i < TB_OFF) { p = gb; off = i - GB_OFF; }
    else if (i < OB_OFF) { p = tb; off = i - TB_OFF; }
    else                 { p = ob; off = i - OB_OFF; }
    bool bf = flags[1] != 0;
    dst[i] = bf ? bf1(((const uint16_t*)p)[off]) : ((const float*)p)[off];
}

// ---------------------------------------------------------------------------
// Kernel 1: embedding gather + sum over L -> x[b][f*16+d] (fp32)
// one thread per (f, b); branches on both dtype flags (wave-uniform).
// ---------------------------------------------------------------------------
__global__ __launch_bounds__(256) void gather_sum(
    const void* __restrict__ ids_raw,
    const void* __restrict__ emb_raw,
    float* __restrict__ xout,
    const int* __restrict__ flags)
{
    const bool i64 = flags[0] != 0;
    const bool bf  = flags[1] != 0;

    int tid = blockIdx.x * 256 + threadIdx.x;   // 0 .. 163839 (exact grid)
    int f = tid >> 14;
    int b = tid & (BATCH - 1);

    int idv[NIDS];
    if (i64) {
        // base byte offset = (f*B+b)*20*8 = 160*(f*B+b) -> 16B aligned
        const int4* p4 = (const int4*)((const long long*)ids_raw +
                                       ((size_t)f * BATCH + b) * NIDS);
        #pragma unroll
        for (int j = 0; j < NIDS / 2; ++j) {
            int4 q = p4[j];            // two int64: (lo,hi,lo,hi)
            idv[2 * j + 0] = q.x;
            idv[2 * j + 1] = q.z;
        }
    } else {
        const int4* p4 = (const int4*)((const int*)ids_raw +
                                       ((size_t)f * BATCH + b) * NIDS);
        #pragma unroll
        for (int j = 0; j < NIDS / 4; ++j) {
            int4 q = p4[j];
            idv[4 * j + 0] = q.x; idv[4 * j + 1] = q.y;
            idv[4 * j + 2] = q.z; idv[4 * j + 3] = q.w;
        }
    }

    float acc[16];
    #pragma unroll
    for (int d = 0; d < 16; ++d) acc[d] = 0.0f;

    if (bf) {
        #pragma unroll 5
        for (int l = 0; l < NIDS; ++l) {
            const uint4* row = (const uint4*)((const uint16_t*)emb_raw +
                                              (size_t)idv[l] * DEMB);
            uint4 r0 = row[0];
            uint4 r1 = row[1];
            acc[0]  += bflo(r0.x); acc[1]  += bfhi(r0.x);
            acc[2]  += bflo(r0.y); acc[3]  += bfhi(r0.y);
            acc[4]  += bflo(r0.z); acc[5]  += bfhi(r0.z);
            acc[6]  += bflo(r0.w); acc[7]  += bfhi(r0.w);
            acc[8]  += bflo(r1.x); acc[9]  += bfhi(r1.x);
            acc[10] += bflo(r1.y); acc[11] += bfhi(r1.y);
            acc[12] += bflo(r1.z); acc[13] += bfhi(r1.z);
            acc[14] += bflo(r1.w); acc[15] += bfhi(r1.w);
        }
    } else {
        #pragma unroll 5
        for (int l = 0; l < NIDS; ++l) {
            const float4* row = (const float4*)((const float*)emb_raw +
                                                (size_t)idv[l] * DEMB);
            float4 r0 = row[0], r1 = row[1], r2 = row[2], r3 = row[3];
            acc[0]  += r0.x; acc[1]  += r0.y; acc[2]  += r0.z; acc[3]  += r0.w;
            acc[4]  += r1.x; acc[5]  += r1.y; acc[6]  += r1.z; acc[7]  += r1.w;
            acc[8]  += r2.x; acc[9]  += r2.y; acc[10] += r2.z; acc[11] += r2.w;
            acc[12] += r3.x; acc[13] += r3.y; acc[14] += r3.z; acc[15] += r3.w;
        }
    }

    float4* dst = (float4*)(xout + (size_t)b * NFEAT + f * DEMB);
    dst[0] = make_float4(acc[0],  acc[1],  acc[2],  acc[3]);
    dst[1] = make_float4(acc[4],  acc[5],  acc[6],  acc[7]);
    dst[2] = make_float4(acc[8],  acc[9],  acc[10], acc[11]);
    dst[3] = make_float4(acc[12], acc[13], acc[14], acc[15]);
}

// ---------------------------------------------------------------------------
// Kernel 2: fused MMoE + towers + ESMM head.
// 16 samples per block, 16 threads per sample (4 samples per wave).
// ---------------------------------------------------------------------------
__global__ __launch_bounds__(256) void moe_fwd(
    const float* __restrict__ xf,
    const float* __restrict__ wf,
    void* __restrict__ out,
    const int* __restrict__ flags)
{
    __shared__ float x_lds[16][NFEAT + 1];       // 10,304 B (pad breaks 160-stride)
    __shared__ float exp_lds[16][NEXP * NS + 4]; // 33,024 B
    __shared__ float gl_lds[16][NG * NEXP];      //  1,536 B
    __shared__ float gate_lds[16][NG * NEXP];    //  1,536 B
    __shared__ float mix_lds[16][NG * NS + 4];   // 12,544 B
    __shared__ float tow_lds[16][NG * NT];       //  6,144 B
    __shared__ float prob_lds[16][6];            //    384 B  (total 65,472 B)

    const int sm = threadIdx.x >> 4;   // sample slot 0..15
    const int t  = threadIdx.x & 15;   // lane within sample
    const int b0 = blockIdx.x * 16;
    const int b  = b0 + sm;

    const float* EW = wf + EW_OFF;
    const float* GW = wf + GW_OFF;
    const float* TW = wf + TW_OFF;
    const float* OW = wf + OW_OFF;
    const float* EB = wf + EB_OFF;
    const float* GB = wf + GB_OFF;
    const float* TB = wf + TB_OFF;
    const float* OB = wf + OB_OFF;

    // stage x (fp32 -> LDS)
    for (int i = threadIdx.x; i < 16 * NFEAT; i += 256) {
        int s = i / NFEAT;
        int k = i - s * NFEAT;
        x_lds[s][k] = xf[(size_t)(b0 + s) * NFEAT + k];
    }
    __syncthreads();

    // gate logits: 24 per sample, thread t handles idx = t, t+16
    for (int idx = t; idx < NG * NEXP; idx += 16) {
        int g = idx >> 3;
        int e = idx & 7;
        const float* W = GW + g * NFEAT * NEXP + e;
        float a = GB[g * NEXP + e];
        #pragma unroll 8
        for (int k = 0; k < NFEAT; ++k) a += x_lds[sm][k] * W[k * NEXP];
        gl_lds[sm][idx] = a;
    }

    // experts: thread t computes s = 4t .. 4t+3 for each expert
    for (int e = 0; e < NEXP; ++e) {
        const float* W = EW + e * NFEAT * NS + 4 * t;
        float a0 = EB[e * NS + 4 * t + 0];
        float a1 = EB[e * NS + 4 * t + 1];
        float a2 = EB[e * NS + 4 * t + 2];
        float a3 = EB[e * NS + 4 * t + 3];
        #pragma unroll 4
        for (int k = 0; k < NFEAT; ++k) {
            float xv = x_lds[sm][k];
            float4 w = *(const float4*)(W + k * NS);
            a0 = fmaf(xv, w.x, a0);
            a1 = fmaf(xv, w.y, a1);
            a2 = fmaf(xv, w.z, a2);
            a3 = fmaf(xv, w.w, a3);
        }
        exp_lds[sm][e * NS + 4 * t + 0] = fmaxf(a0, 0.0f);
        exp_lds[sm][e * NS + 4 * t + 1] = fmaxf(a1, 0.0f);
        exp_lds[sm][e * NS + 4 * t + 2] = fmaxf(a2, 0.0f);
        exp_lds[sm][e * NS + 4 * t + 3] = fmaxf(a3, 0.0f);
    }
    __syncthreads();

    // gate softmax over E, threads t<3 (g = t)
    if (t < NG) {
        int g = t;
        float m = -1e30f;
        #pragma unroll
        for (int e = 0; e < NEXP; ++e) m = fmaxf(m, gl_lds[sm][g * 8 + e]);
        float ex[NEXP];
        float ssum = 0.0f;
        #pragma unroll
        for (int e = 0; e < NEXP; ++e) {
            ex[e] = __expf(gl_lds[sm][g * 8 + e] - m);
            ssum += ex[e];
        }
        float inv = 1.0f / ssum;
        #pragma unroll
        for (int e = 0; e < NEXP; ++e) gate_lds[sm][g * 8 + e] = ex[e] * inv;
    }
    __syncthreads();

    // mix[g][s] = sum_e gate[g][e] * experts[e][s]; thread t does s = 4t..4t+3
    for (int g = 0; g < NG; ++g) {
        float m0 = 0.f, m1 = 0.f, m2 = 0.f, m3 = 0.f;
        #pragma unroll
        for (int e = 0; e < NEXP; ++e) {
            float gv = gate_lds[sm][g * 8 + e];
            m0 = fmaf(gv, exp_lds[sm][e * NS + 4 * t + 0], m0);
            m1 = fmaf(gv, exp_lds[sm][e * NS + 4 * t + 1], m1);
            m2 = fmaf(gv, exp_lds[sm][e * NS + 4 * t + 2], m2);
            m3 = fmaf(gv, exp_lds[sm][e * NS + 4 * t + 3], m3);
        }
        mix_lds[sm][g * NS + 4 * t + 0] = m0;
        mix_lds[sm][g * NS + 4 * t + 1] = m1;
        mix_lds[sm][g * NS + 4 * t + 2] = m2;
        mix_lds[sm][g * NS + 4 * t + 3] = m3;
    }
    __syncthreads();

    // tower: 96 outputs per sample; thread t handles idx = t, t+16, ..., t+80
    for (int idx = t; idx < NG * NT; idx += 16) {
        int g  = idx >> 5;
        int tt = idx & 31;
        const float* W = TW + g * NS * NT + tt;
        float a = TB[g * NT + tt];
        #pragma unroll 8
        for (int s = 0; s < NS; ++s) a = fmaf(mix_lds[sm][g * NS + s], W[s * NT], a);
        tow_lds[sm][idx] = fmaxf(a, 0.0f);
    }
    __syncthreads();

    // final 2-way logits + softmax + clip, threads t<3 (g = t)
    if (t < NG) {
        int g = t;
        float l0 = OB[g * 2 + 0];
        float l1 = OB[g * 2 + 1];
        const float* W = OW + g * NT * 2;
        #pragma unroll
        for (int tt = 0; tt < NT; ++tt) {
            float tv = tow_lds[sm][g * NT + tt];
            l0 = fmaf(tv, W[tt * 2 + 0], l0);
            l1 = fmaf(tv, W[tt * 2 + 1], l1);
        }
        float m  = fmaxf(l0, l1);
        float e0 = __expf(l0 - m);
        float e1 = __expf(l1 - m);
        float inv = 1.0f / (e0 + e1);
        float p0 = e0 * inv;
        float p1 = e1 * inv;
        // clip(softmax, 1e-15, 1-1e-15); 1-1e-15 rounds to 1.0f in fp32
        p0 = fminf(fmaxf(p0, 1e-15f), 1.0f);
        p1 = fminf(fmaxf(p1, 1e-15f), 1.0f);
        prob_lds[sm][g * 2 + 0] = p0;
        prob_lds[sm][g * 2 + 1] = p1;
    }
    __syncthreads();

    // output assembly: [ctr0, ctr1, ctr1, cvr0, cvr1, cvr1, 1-ctcvr1, ctcvr1, ctcvr1, imp1]
    if (t < 10) {
        float ctr0 = prob_lds[sm][0], ctr1 = prob_lds[sm][1];
        float cvr0 = prob_lds[sm][2], cvr1 = prob_lds[sm][3];
        float imp1 = prob_lds[sm][5];
        float ctcvr1 = ctr1 * cvr1;
        float v;
        switch (t) {
            case 0: v = ctr0; break;
            case 1: v = ctr1; break;
            case 2: v = ctr1; break;
            case 3: v = cvr0; break;
            case 4: v = cvr1; break;
            case 5: v = cvr1; break;
            case 6: v = 1.0f - ctcvr1; break;
            case 7: v = ctcvr1; break;
            case 8: v = ctcvr1; break;
            default: v = imp1; break;
        }
        if (flags[1]) ((uint16_t*)out)[(size_t)b * 10 + t] = f2bf(v);
        else          ((float*)out)[(size_t)b * 10 + t]    = v;
    }
}

// ---------------------------------------------------------------------------
extern "C" void kernel_launch(void* const* d_in, const int* in_sizes, int n_in,
                              void* d_out, int out_size, void* d_ws, size_t ws_size,
                              hipStream_t stream) {
    const void* ids = d_in[0];
    const void* emb = d_in[1];

    float* xf    = (float*)d_ws;
    float* wf    = (float*)((char*)d_ws + WF_OFF_B);
    int*   flags = (int*)((char*)d_ws + FLAG_OFF_B);

    sniff_dtypes<<<1, 64, 0, stream>>>((const uint32_t*)ids, (const uint32_t*)emb, flags);
    convert_weights<<<(W_TOTAL + 255) / 256, 256, 0, stream>>>(
        d_in[2], d_in[3], d_in[4], d_in[5], d_in[6], d_in[7], d_in[8], d_in[9], wf, flags);
    gather_sum<<<(NFIELD * BATCH) / 256, 256, 0, stream>>>(ids, emb, xf, flags);
    moe_fwd<<<BATCH / 16, 256, 0, stream>>>(xf, wf, d_out, flags);
}

// Round 5
// 209.475 us; speedup vs baseline: 1.7852x; 1.7852x over previous
//
#include <hip/hip_runtime.h>
#include <hip/hip_bf16.h>
#include <cstdint>
#include <cstddef>

// Problem constants
#define NFIELD 10
#define BATCH  16384
#define NIDS   20
#define DEMB   16
#define NFEAT  160   // NFIELD * DEMB
#define NEXP   8
#define NS     64
#define NG     3
#define NT     32

// workspace layout (bytes), all regions 16B-aligned
#define XB        ((size_t)BATCH * NFEAT * 2)      // bf16 x: 5,242,880
#define BP_OFF_B  XB                               // main B-pack: 34*5*64*8*2 = 174,080
#define BM_OFF_B  (BP_OFF_B + 174080)              // main bias fp32[544] = 2,176
#define BT_OFF_B  (BM_OFF_B + 2176)                // tower B-pack: 3*2*2*64*8*2 = 12,288
#define TB2_OFF_B (BT_OFF_B + 12288)               // tower bias fp32[96] = 384
#define OWF_OFF_B (TB2_OFF_B + 384)                // out w fp32[192] = 768
#define OBF_OFF_B (OWF_OFF_B + 768)                // out b fp32[6] = 24 (pad to 32)
#define FLG_OFF_B (OBF_OFF_B + 32)

typedef short bfrag __attribute__((ext_vector_type(8)));  // 8 bf16 (4 VGPRs)
typedef float f32x4 __attribute__((ext_vector_type(4)));

__device__ __forceinline__ float bflo(uint32_t u) {
    union { uint32_t u; float f; } c; c.u = u << 16; return c.f;
}
__device__ __forceinline__ float bfhi(uint32_t u) {
    union { uint32_t u; float f; } c; c.u = u & 0xffff0000u; return c.f;
}
__device__ __forceinline__ float bf1(uint16_t v) {
    union { uint32_t u; float f; } c; c.u = ((uint32_t)v) << 16; return c.f;
}
__device__ __forceinline__ uint16_t f2bf(float f) {
    union { float f; uint32_t u; } c; c.f = f;
    uint32_t r = c.u + 0x7fffu + ((c.u >> 16) & 1u);  // RTNE
    return (uint16_t)(r >> 16);
}
// dtype-dispatched element loads (bf = buffer holds bf16, else fp32)
__device__ __forceinline__ float ldw(const void* p, int i, bool bf) {
    return bf ? bf1(((const uint16_t*)p)[i]) : ((const float*)p)[i];
}
__device__ __forceinline__ uint16_t ldb16(const void* p, int i, bool bf) {
    return bf ? ((const uint16_t*)p)[i] : f2bf(((const float*)p)[i]);
}

// ---------------------------------------------------------------------------
// Kernel S: sniff dtypes. flags[0]=1 if ids int64; flags[1]=1 if floats bf16.
// (verified logic from the round-2 passing kernel)
// ---------------------------------------------------------------------------
__global__ __launch_bounds__(64) void sniff_dtypes(
    const uint32_t* __restrict__ ids_w,
    const uint32_t* __restrict__ emb_w,
    int* __restrict__ flags)
{
    int t = threadIdx.x;
    size_t p = (size_t)t * 25000;          // in-bounds under both interpretations
    uint32_t hi = ids_w[2 * p + 1];
    int n_hi = __popcll(__ballot(hi != 0));

    size_t q = (size_t)t * 125000;         // <= 31.5 MB, in-bounds both ways
    uint32_t w = emb_w[q];
    uint32_t v = (w >> 8) & 0x7Fu;         // bf16 exponent bits vs fp32 mantissa
    int n_bf = __popcll(__ballot(v >= 0x3Bu && v <= 0x3Fu));

    if (t == 0) {
        flags[0] = (n_hi < 8)   ? 1 : 0;
        flags[1] = (n_bf >= 32) ? 1 : 0;
    }
}

// ---------------------------------------------------------------------------
// Kernel P: pack weights (either dtype) into MFMA B-frag bf16 + fp32 biases.
// Main GEMM Wc[k=160][n=544]: n<512 -> expert_w[n>>6][k][n&63];
//   512<=n<536 -> gate_w[(n-512)>>3][k][(n-512)&7]; else 0.
// Frag: [(nt*5+ks)*64+lane]*8+j, element = Wc[ks*32+(lane>>4)*8+j][nt*16+(lane&15)]
// ---------------------------------------------------------------------------
__global__ __launch_bounds__(256) void pack_weights(
    const void* __restrict__ ew, const void* __restrict__ eb,
    const void* __restrict__ gw, const void* __restrict__ gb,
    const void* __restrict__ tw, const void* __restrict__ tb,
    const void* __restrict__ ow, const void* __restrict__ ob,
    uint16_t* __restrict__ bp, float* __restrict__ bm,
    uint16_t* __restrict__ bt, float* __restrict__ tb2,
    float* __restrict__ owf, float* __restrict__ obf,
    const int* __restrict__ flags)
{
    const bool bf = flags[1] != 0;
    int i = blockIdx.x * 256 + threadIdx.x;
    if (i < 10880) {                       // main B-pack: 34 tiles * 5 ksteps * 64 lanes
        int nt = i / 320, rem = i % 320;
        int ks = rem / 64, l = rem % 64;
        int n  = nt * 16 + (l & 15);
        int kb = ks * 32 + ((l >> 4) * 8);
        uint16_t v[8];
        #pragma unroll
        for (int j = 0; j < 8; ++j) {
            int k = kb + j;
            uint16_t x;
            if (n < 512)      x = ldb16(ew, (n >> 6) * 10240 + k * 64 + (n & 63), bf);
            else if (n < 536) x = ldb16(gw, ((n - 512) >> 3) * 1280 + k * 8 + ((n - 512) & 7), bf);
            else              x = 0;
            v[j] = x;
        }
        uint4 o;
        o.x = (uint32_t)v[0] | ((uint32_t)v[1] << 16);
        o.y = (uint32_t)v[2] | ((uint32_t)v[3] << 16);
        o.z = (uint32_t)v[4] | ((uint32_t)v[5] << 16);
        o.w = (uint32_t)v[6] | ((uint32_t)v[7] << 16);
        ((uint4*)bp)[i] = o;
    } else if (i < 11648) {                // tower B-pack: 3g * 2nt * 2ks * 64 lanes
        int it = i - 10880;
        int g = it / 256, rem = it % 256;
        int ntile = rem / 128, ks = (rem / 64) & 1, l = rem % 64;
        int t  = ntile * 16 + (l & 15);
        int sb = ks * 32 + ((l >> 4) * 8);
        uint16_t v[8];
        #pragma unroll
        for (int j = 0; j < 8; ++j)
            v[j] = ldb16(tw, g * 2048 + (sb + j) * 32 + t, bf);
        uint4 o;
        o.x = (uint32_t)v[0] | ((uint32_t)v[1] << 16);
        o.y = (uint32_t)v[2] | ((uint32_t)v[3] << 16);
        o.z = (uint32_t)v[4] | ((uint32_t)v[5] << 16);
        o.w = (uint32_t)v[6] | ((uint32_t)v[7] << 16);
        ((uint4*)bt)[it] = o;
    } else if (i < 12192) {                // main bias [544]
        int n = i - 11648;
        bm[n] = (n < 512) ? ldw(eb, n, bf) : (n < 536 ? ldw(gb, n - 512, bf) : 0.0f);
    } else if (i < 12288) {                // tower bias [96]
        int n = i - 12192; tb2[n] = ldw(tb, n, bf);
    } else if (i < 12480) {                // out w [192]
        int n = i - 12288; owf[n] = ldw(ow, n, bf);
    } else if (i < 12486) {                // out b [6]
        int n = i - 12480; obf[n] = ldw(ob, n, bf);
    }
}

// ---------------------------------------------------------------------------
// Kernel 1: embedding gather + sum over L -> x[b][f*16+d] (bf16 out)
// dual dtype paths for ids (int32/int64) and emb (bf16/fp32)
// ---------------------------------------------------------------------------
__global__ __launch_bounds__(256) void gather_sum(
    const void* __restrict__ ids_raw,
    const void* __restrict__ emb_raw,
    uint16_t* __restrict__ xout,
    const int* __restrict__ flags)
{
    const bool i64 = flags[0] != 0;
    const bool bf  = flags[1] != 0;
    int tid = blockIdx.x * 256 + threadIdx.x;   // exact grid 163840
    int f = tid >> 14;
    int b = tid & (BATCH - 1);

    int idv[NIDS];
    if (i64) {
        const int4* p4 = (const int4*)((const long long*)ids_raw +
                                       ((size_t)f * BATCH + b) * NIDS);
        #pragma unroll
        for (int j = 0; j < NIDS / 2; ++j) {
            int4 q = p4[j];
            idv[2 * j + 0] = q.x;
            idv[2 * j + 1] = q.z;
        }
    } else {
        const int4* p4 = (const int4*)((const int*)ids_raw +
                                       ((size_t)f * BATCH + b) * NIDS);
        #pragma unroll
        for (int j = 0; j < NIDS / 4; ++j) {
            int4 q = p4[j];
            idv[4 * j + 0] = q.x; idv[4 * j + 1] = q.y;
            idv[4 * j + 2] = q.z; idv[4 * j + 3] = q.w;
        }
    }

    float acc[16];
    #pragma unroll
    for (int d = 0; d < 16; ++d) acc[d] = 0.0f;

    if (bf) {
        #pragma unroll 5
        for (int l = 0; l < NIDS; ++l) {
            const uint4* row = (const uint4*)((const uint16_t*)emb_raw +
                                              (size_t)idv[l] * DEMB);
            uint4 r0 = row[0];
            uint4 r1 = row[1];
            acc[0]  += bflo(r0.x); acc[1]  += bfhi(r0.x);
            acc[2]  += bflo(r0.y); acc[3]  += bfhi(r0.y);
            acc[4]  += bflo(r0.z); acc[5]  += bfhi(r0.z);
            acc[6]  += bflo(r0.w); acc[7]  += bfhi(r0.w);
            acc[8]  += bflo(r1.x); acc[9]  += bfhi(r1.x);
            acc[10] += bflo(r1.y); acc[11] += bfhi(r1.y);
            acc[12] += bflo(r1.z); acc[13] += bfhi(r1.z);
            acc[14] += bflo(r1.w); acc[15] += bfhi(r1.w);
        }
    } else {
        #pragma unroll 5
        for (int l = 0; l < NIDS; ++l) {
            const float4* row = (const float4*)((const float*)emb_raw +
                                                (size_t)idv[l] * DEMB);
            float4 r0 = row[0], r1 = row[1], r2 = row[2], r3 = row[3];
            acc[0]  += r0.x; acc[1]  += r0.y; acc[2]  += r0.z; acc[3]  += r0.w;
            acc[4]  += r1.x; acc[5]  += r1.y; acc[6]  += r1.z; acc[7]  += r1.w;
            acc[8]  += r2.x; acc[9]  += r2.y; acc[10] += r2.z; acc[11] += r2.w;
            acc[12] += r3.x; acc[13] += r3.y; acc[14] += r3.z; acc[15] += r3.w;
        }
    }

    uint32_t p[8];
    #pragma unroll
    for (int j = 0; j < 8; ++j)
        p[j] = (uint32_t)f2bf(acc[2 * j]) | ((uint32_t)f2bf(acc[2 * j + 1]) << 16);

    uint4* dst = (uint4*)(xout + (size_t)b * NFEAT + f * DEMB);
    dst[0] = make_uint4(p[0], p[1], p[2], p[3]);
    dst[1] = make_uint4(p[4], p[5], p[6], p[7]);
}

// ---------------------------------------------------------------------------
// Kernel 2: MFMA MMoE + checkers + block-uniform VALU fallback (originals,
// dtype-dispatched). 32 samples/block, 4 waves. Output dtype per flags[1].
// ---------------------------------------------------------------------------
__global__ __launch_bounds__(256) void moe_fwd(
    const uint16_t* __restrict__ xbf,
    const uint16_t* __restrict__ bp,   // main B-pack
    const float*    __restrict__ bm,   // main bias [544] fp32
    const uint16_t* __restrict__ btw,  // tower B-pack
    const float*    __restrict__ btb,  // tower bias [96] fp32
    const float*    __restrict__ owf,  // out w [192] fp32
    const float*    __restrict__ obf,  // out b [6] fp32
    const void* __restrict__ ew,       // originals (checker/fallback)
    const void* __restrict__ eb,
    const void* __restrict__ gw,
    const void* __restrict__ gb,
    const void* __restrict__ tw,
    const void* __restrict__ tb,
    const int* __restrict__ flags,
    void* __restrict__ out)
{
    __shared__ uint16_t exp_lds[32][520];   // 33,280 B
    __shared__ float    gate_lds[32][33];   //  4,224 B
    __shared__ uint16_t mix_lds[32][200];   // 12,800 B (cols 0..159 reused as x-scratch in fallback)
    __shared__ float    tow_lds[32][100];   // 12,800 B
    __shared__ float    prob_lds[32][6];    //    768 B
    __shared__ int      badf, badt;         // total 63,880 B

    const bool bfw = flags[1] != 0;
    const int tid = threadIdx.x;
    const int w = tid >> 6, l = tid & 63;
    const int lm = l & 15, q = l >> 4;
    const int b0 = blockIdx.x * 32;
    const int mrow = (w & 1) * 16;
    const int nhalf = w >> 1;

    if (tid == 0) { badf = 0; badt = 0; }

    // ---- A fragments: rows b0+mrow+lm, all 5 K-steps, held in registers ----
    bfrag a[5];
    {
        const uint16_t* xr = xbf + (size_t)(b0 + mrow + lm) * NFEAT + q * 8;
        #pragma unroll
        for (int ks = 0; ks < 5; ++ks)
            a[ks] = *(const bfrag*)(xr + ks * 32);
    }

    // ---- expert + gate MFMA GEMM: 17 N-tiles per wave ----
    const int nt0 = nhalf * 17;
    for (int it = 0; it < 17; ++it) {
        int nt = nt0 + it;
        f32x4 acc = {0.0f, 0.0f, 0.0f, 0.0f};
        const bfrag* bpp = (const bfrag*)bp + (size_t)(nt * 5) * 64 + l;
        #pragma unroll
        for (int ks = 0; ks < 5; ++ks) {
            bfrag b = bpp[ks * 64];
            acc = __builtin_amdgcn_mfma_f32_16x16x32_bf16(a[ks], b, acc, 0, 0, 0);
        }
        int col = nt * 16 + lm;
        float bias = bm[col];
        if (col < 512) {
            #pragma unroll
            for (int r = 0; r < 4; ++r)
                exp_lds[mrow + q * 4 + r][col] = f2bf(fmaxf(acc[r] + bias, 0.0f));
        } else {
            #pragma unroll
            for (int r = 0; r < 4; ++r)
                gate_lds[mrow + q * 4 + r][col - 512] = acc[r] + bias;
        }
    }
    __syncthreads();

    // ---- checker: recompute scattered entries from ORIGINAL weights ----
    if (tid < 64) {
        int s = tid & 31;
        int c = (tid * 67) & 511;            // 64 distinct cols
        int e = c >> 6, ss = c & 63;
        const uint16_t* xr = xbf + (size_t)(b0 + s) * NFEAT;
        float acal = ldw(eb, c, bfw);
        for (int k = 0; k < NFEAT; ++k)
            acal = fmaf(bf1(xr[k]), ldw(ew, e * 10240 + k * 64 + ss, bfw), acal);
        float want = fmaxf(acal, 0.0f);
        float got  = bf1(exp_lds[s][c]);
        if (fabsf(want - got) > 0.06f + 0.01f * fabsf(want)) badf = 1;
    } else if (tid < 88) {
        int idx = tid - 64;                  // 0..23 (all gate logits)
        int s   = (tid * 5) & 31;
        int g = idx >> 3, e = idx & 7;
        const uint16_t* xr = xbf + (size_t)(b0 + s) * NFEAT;
        float acal = ldw(gb, idx, bfw);
        for (int k = 0; k < NFEAT; ++k)
            acal = fmaf(bf1(xr[k]), ldw(gw, g * 1280 + k * 8 + e, bfw), acal);
        if (fabsf(acal - gate_lds[s][idx]) > 0.04f + 0.01f * fabsf(acal)) badf = 1;
    }
    __syncthreads();

    // ---- VALU fallback for experts + gates (block-uniform) ----
    if (badf) {
        uint16_t* xs = &mix_lds[0][0];       // reuse mix_lds as x scratch
        for (int i = tid; i < 32 * NFEAT; i += 256) {
            int s = i / NFEAT, k = i - s * NFEAT;
            xs[s * 200 + k] = xbf[(size_t)(b0 + s) * NFEAT + k];
        }
        __syncthreads();
        int s2 = tid >> 3, j2 = tid & 7;
        for (int c = j2; c < 512; c += 8) {
            int e = c >> 6, ss = c & 63;
            float acal = ldw(eb, c, bfw);
            #pragma unroll 4
            for (int k = 0; k < NFEAT; ++k)
                acal = fmaf(bf1(xs[s2 * 200 + k]), ldw(ew, e * 10240 + k * 64 + ss, bfw), acal);
            exp_lds[s2][c] = f2bf(fmaxf(acal, 0.0f));
        }
        if (j2 < 3) {
            int g = j2;
            for (int e = 0; e < 8; ++e) {
                float acal = ldw(gb, g * 8 + e, bfw);
                #pragma unroll 4
                for (int k = 0; k < NFEAT; ++k)
                    acal = fmaf(bf1(xs[s2 * 200 + k]), ldw(gw, g * 1280 + k * 8 + e, bfw), acal);
                gate_lds[s2][g * 8 + e] = acal;
            }
        }
        __syncthreads();
    }

    const int sm = tid >> 3, j = tid & 7;   // 32 samples x 8 threads

    // ---- gate softmax (j<3 -> g=j) ----
    if (j < 3) {
        float* gl = &gate_lds[sm][j * 8];
        float m = gl[0];
        #pragma unroll
        for (int e = 1; e < 8; ++e) m = fmaxf(m, gl[e]);
        float ex[8], s = 0.0f;
        #pragma unroll
        for (int e = 0; e < 8; ++e) { ex[e] = __expf(gl[e] - m); s += ex[e]; }
        float inv = 1.0f / s;
        #pragma unroll
        for (int e = 0; e < 8; ++e) gl[e] = ex[e] * inv;
    }
    __syncthreads();

    // ---- mix[g][s]: thread j does s = j*8..j*8+7 for all g; bf16 out ----
    for (int g = 0; g < NG; ++g) {
        float m8[8];
        #pragma unroll
        for (int i = 0; i < 8; ++i) m8[i] = 0.0f;
        #pragma unroll
        for (int e = 0; e < NEXP; ++e) {
            float gv = gate_lds[sm][g * 8 + e];
            uint4 u = *(const uint4*)&exp_lds[sm][e * 64 + j * 8];
            m8[0] = fmaf(gv, bflo(u.x), m8[0]); m8[1] = fmaf(gv, bfhi(u.x), m8[1]);
            m8[2] = fmaf(gv, bflo(u.y), m8[2]); m8[3] = fmaf(gv, bfhi(u.y), m8[3]);
            m8[4] = fmaf(gv, bflo(u.z), m8[4]); m8[5] = fmaf(gv, bfhi(u.z), m8[5]);
            m8[6] = fmaf(gv, bflo(u.w), m8[6]); m8[7] = fmaf(gv, bfhi(u.w), m8[7]);
        }
        uint4 o;
        o.x = (uint32_t)f2bf(m8[0]) | ((uint32_t)f2bf(m8[1]) << 16);
        o.y = (uint32_t)f2bf(m8[2]) | ((uint32_t)f2bf(m8[3]) << 16);
        o.z = (uint32_t)f2bf(m8[4]) | ((uint32_t)f2bf(m8[5]) << 16);
        o.w = (uint32_t)f2bf(m8[6]) | ((uint32_t)f2bf(m8[7]) << 16);
        *(uint4*)&mix_lds[sm][g * 64 + j * 8] = o;
    }
    __syncthreads();

    // ---- tower MFMA: 12 units (3g x 2mt x 2nt), wave w does u = w, w+4, w+8 ----
    for (int u = w; u < 12; u += 4) {
        int g = u >> 2, mt = (u >> 1) & 1, ntile = u & 1;
        f32x4 acc = {0.0f, 0.0f, 0.0f, 0.0f};
        #pragma unroll
        for (int ks = 0; ks < 2; ++ks) {
            bfrag av = *(const bfrag*)&mix_lds[mt * 16 + lm][g * 64 + ks * 32 + q * 8];
            bfrag bv = *(const bfrag*)(btw + (size_t)((((g * 2 + ntile) * 2 + ks) * 64 + l)) * 8);
            acc = __builtin_amdgcn_mfma_f32_16x16x32_bf16(av, bv, acc, 0, 0, 0);
        }
        int t = ntile * 16 + lm;
        float bias = btb[g * 32 + t];
        #pragma unroll
        for (int r = 0; r < 4; ++r)
            tow_lds[mt * 16 + q * 4 + r][g * 32 + t] = fmaxf(acc[r] + bias, 0.0f);
    }
    __syncthreads();

    // ---- tower checker (originals) ----
    if (tid < 64) {
        int s   = tid & 31;
        int idx = (tid * 29) % 96;
        int g = idx >> 5, t = idx & 31;
        float acal = ldw(tb, g * 32 + t, bfw);
        for (int ss = 0; ss < NS; ++ss)
            acal = fmaf(bf1(mix_lds[s][g * 64 + ss]), ldw(tw, g * 2048 + ss * 32 + t, bfw), acal);
        float want = fmaxf(acal, 0.0f);
        if (fabsf(want - tow_lds[s][g * 32 + t]) > 0.04f + 0.01f * fabsf(want)) badt = 1;
    }
    __syncthreads();

    // ---- VALU fallback for tower ----
    if (badt) {
        int s2 = tid >> 3, j2 = tid & 7;
        for (int idx = j2; idx < 96; idx += 8) {
            int g = idx >> 5, t = idx & 31;
            float acal = ldw(tb, g * 32 + t, bfw);
            #pragma unroll 4
            for (int ss = 0; ss < NS; ++ss)
                acal = fmaf(bf1(mix_lds[s2][g * 64 + ss]), ldw(tw, g * 2048 + ss * 32 + t, bfw), acal);
            tow_lds[s2][g * 32 + t] = fmaxf(acal, 0.0f);
        }
        __syncthreads();
    }

    // ---- out head: j<3 -> g=j: 2 logits, softmax, clip ----
    if (j < 3) {
        int g = j;
        float l0 = obf[2 * g], l1 = obf[2 * g + 1];
        #pragma unroll 8
        for (int t = 0; t < NT; ++t) {
            float tv = tow_lds[sm][g * 32 + t];
            l0 = fmaf(tv, owf[g * 64 + 2 * t], l0);
            l1 = fmaf(tv, owf[g * 64 + 2 * t + 1], l1);
        }
        float m  = fmaxf(l0, l1);
        float e0 = __expf(l0 - m);
        float e1 = __expf(l1 - m);
        float inv = 1.0f / (e0 + e1);
        float p0 = fminf(fmaxf(e0 * inv, 1e-15f), 1.0f);
        float p1 = fminf(fmaxf(e1 * inv, 1e-15f), 1.0f);
        prob_lds[sm][2 * g + 0] = p0;
        prob_lds[sm][2 * g + 1] = p1;
    }
    __syncthreads();

    // ---- assemble 10 outputs per sample, dtype per flags[1] ----
    {
        float ctr0 = prob_lds[sm][0], ctr1 = prob_lds[sm][1];
        float cvr0 = prob_lds[sm][2], cvr1 = prob_lds[sm][3];
        float imp1 = prob_lds[sm][5];
        float ctcvr1 = ctr1 * cvr1;
        for (int o = j; o < 10; o += 8) {
            float v;
            switch (o) {
                case 0: v = ctr0; break;
                case 1: v = ctr1; break;
                case 2: v = ctr1; break;
                case 3: v = cvr0; break;
                case 4: v = cvr1; break;
                case 5: v = cvr1; break;
                case 6: v = 1.0f - ctcvr1; break;
                case 7: v = ctcvr1; break;
                case 8: v = ctcvr1; break;
                default: v = imp1; break;
            }
            if (bfw) ((uint16_t*)out)[(size_t)(b0 + sm) * 10 + o] = f2bf(v);
            else     ((float*)out)[(size_t)(b0 + sm) * 10 + o]    = v;
        }
    }
}

// ---------------------------------------------------------------------------
extern "C" void kernel_launch(void* const* d_in, const int* in_sizes, int n_in,
                              void* d_out, int out_size, void* d_ws, size_t ws_size,
                              hipStream_t stream) {
    const void* ids = d_in[0];
    const void* emb = d_in[1];

    char* ws = (char*)d_ws;
    uint16_t* xbf = (uint16_t*)ws;
    uint16_t* bpk = (uint16_t*)(ws + BP_OFF_B);
    float*    bm  = (float*)(ws + BM_OFF_B);
    uint16_t* btw = (uint16_t*)(ws + BT_OFF_B);
    float*    tb2 = (float*)(ws + TB2_OFF_B);
    float*    owf = (float*)(ws + OWF_OFF_B);
    float*    obf = (float*)(ws + OBF_OFF_B);
    int*    flags = (int*)(ws + FLG_OFF_B);

    sniff_dtypes<<<1, 64, 0, stream>>>((const uint32_t*)ids, (const uint32_t*)emb, flags);
    pack_weights<<<49, 256, 0, stream>>>(
        d_in[2], d_in[3], d_in[4], d_in[5], d_in[6], d_in[7], d_in[8], d_in[9],
        bpk, bm, btw, tb2, owf, obf, flags);
    gather_sum<<<(NFIELD * BATCH) / 256, 256, 0, stream>>>(ids, emb, xbf, flags);
    moe_fwd<<<BATCH / 32, 256, 0, stream>>>(
        xbf, bpk, bm, btw, tb2, owf, obf,
        d_in[2], d_in[3], d_in[4], d_in[5], d_in[6], d_in[7],
        flags, d_out);
}

// Round 6
// 204.911 us; speedup vs baseline: 1.8249x; 1.0223x over previous
//
#include <hip/hip_runtime.h>
#include <hip/hip_bf16.h>
#include <cstdint>
#include <cstddef>

// Problem constants
#define NFIELD 10
#define BATCH  16384
#define NIDS   20
#define DEMB   16
#define NFEAT  160   // NFIELD * DEMB
#define NEXP   8
#define NS     64
#define NG     3
#define NT     32

// workspace layout (bytes), all regions 16B-aligned
#define XB        ((size_t)BATCH * NFEAT * 2)      // bf16 x: 5,242,880
#define BP_OFF_B  XB                               // main B-pack: 34*5*64*8*2 = 174,080
#define BM_OFF_B  (BP_OFF_B + 174080)              // main bias fp32[544] = 2,176
#define BT_OFF_B  (BM_OFF_B + 2176)                // tower B-pack: 3*2*2*64*8*2 = 12,288
#define TB2_OFF_B (BT_OFF_B + 12288)               // tower bias fp32[96] = 384
#define OWF_OFF_B (TB2_OFF_B + 384)                // out w fp32[192] = 768
#define OBF_OFF_B (OWF_OFF_B + 768)                // out b fp32[6] = 24 (pad to 32)
#define FLG_OFF_B (OBF_OFF_B + 32)

typedef short bfrag __attribute__((ext_vector_type(8)));  // 8 bf16 (4 VGPRs)
typedef float f32x4 __attribute__((ext_vector_type(4)));

__device__ __forceinline__ float bflo(uint32_t u) {
    union { uint32_t u; float f; } c; c.u = u << 16; return c.f;
}
__device__ __forceinline__ float bfhi(uint32_t u) {
    union { uint32_t u; float f; } c; c.u = u & 0xffff0000u; return c.f;
}
__device__ __forceinline__ float bf1(uint16_t v) {
    union { uint32_t u; float f; } c; c.u = ((uint32_t)v) << 16; return c.f;
}
__device__ __forceinline__ uint16_t f2bf(float f) {
    union { float f; uint32_t u; } c; c.f = f;
    uint32_t r = c.u + 0x7fffu + ((c.u >> 16) & 1u);  // RTNE
    return (uint16_t)(r >> 16);
}
// dtype-dispatched element loads (bf = buffer holds bf16, else fp32)
__device__ __forceinline__ float ldw(const void* p, int i, bool bf) {
    return bf ? bf1(((const uint16_t*)p)[i]) : ((const float*)p)[i];
}
__device__ __forceinline__ uint16_t ldb16(const void* p, int i, bool bf) {
    return bf ? ((const uint16_t*)p)[i] : f2bf(((const float*)p)[i]);
}

// ---------------------------------------------------------------------------
// Kernel S: sniff dtypes. flags[0]=1 if ids int64; flags[1]=1 if floats bf16.
// ---------------------------------------------------------------------------
__global__ __launch_bounds__(64) void sniff_dtypes(
    const uint32_t* __restrict__ ids_w,
    const uint32_t* __restrict__ emb_w,
    int* __restrict__ flags)
{
    int t = threadIdx.x;
    size_t p = (size_t)t * 25000;          // in-bounds under both interpretations
    uint32_t hi = ids_w[2 * p + 1];
    int n_hi = __popcll(__ballot(hi != 0));

    size_t q = (size_t)t * 125000;         // <= 31.5 MB, in-bounds both ways
    uint32_t w = emb_w[q];
    uint32_t v = (w >> 8) & 0x7Fu;         // bf16 exponent bits vs fp32 mantissa
    int n_bf = __popcll(__ballot(v >= 0x3Bu && v <= 0x3Fu));

    if (t == 0) {
        flags[0] = (n_hi < 8)   ? 1 : 0;
        flags[1] = (n_bf >= 32) ? 1 : 0;
    }
}

// ---------------------------------------------------------------------------
// Kernel P: pack weights (either dtype) into MFMA B-frag bf16 + fp32 biases.
// Main GEMM Wc[k=160][n=544]: n<512 -> expert_w[n>>6][k][n&63];
//   512<=n<536 -> gate_w[(n-512)>>3][k][(n-512)&7]; else 0.
// Frag: [(nt*5+ks)*64+lane]*8+j, element = Wc[ks*32+(lane>>4)*8+j][nt*16+(lane&15)]
// ---------------------------------------------------------------------------
__global__ __launch_bounds__(256) void pack_weights(
    const void* __restrict__ ew, const void* __restrict__ eb,
    const void* __restrict__ gw, const void* __restrict__ gb,
    const void* __restrict__ tw, const void* __restrict__ tb,
    const void* __restrict__ ow, const void* __restrict__ ob,
    uint16_t* __restrict__ bp, float* __restrict__ bm,
    uint16_t* __restrict__ bt, float* __restrict__ tb2,
    float* __restrict__ owf, float* __restrict__ obf,
    const int* __restrict__ flags)
{
    const bool bf = flags[1] != 0;
    int i = blockIdx.x * 256 + threadIdx.x;
    if (i < 10880) {                       // main B-pack: 34 tiles * 5 ksteps * 64 lanes
        int nt = i / 320, rem = i % 320;
        int ks = rem / 64, l = rem % 64;
        int n  = nt * 16 + (l & 15);
        int kb = ks * 32 + ((l >> 4) * 8);
        uint16_t v[8];
        #pragma unroll
        for (int j = 0; j < 8; ++j) {
            int k = kb + j;
            uint16_t x;
            if (n < 512)      x = ldb16(ew, (n >> 6) * 10240 + k * 64 + (n & 63), bf);
            else if (n < 536) x = ldb16(gw, ((n - 512) >> 3) * 1280 + k * 8 + ((n - 512) & 7), bf);
            else              x = 0;
            v[j] = x;
        }
        uint4 o;
        o.x = (uint32_t)v[0] | ((uint32_t)v[1] << 16);
        o.y = (uint32_t)v[2] | ((uint32_t)v[3] << 16);
        o.z = (uint32_t)v[4] | ((uint32_t)v[5] << 16);
        o.w = (uint32_t)v[6] | ((uint32_t)v[7] << 16);
        ((uint4*)bp)[i] = o;
    } else if (i < 11648) {                // tower B-pack: 3g * 2nt * 2ks * 64 lanes
        int it = i - 10880;
        int g = it / 256, rem = it % 256;
        int ntile = rem / 128, ks = (rem / 64) & 1, l = rem % 64;
        int t  = ntile * 16 + (l & 15);
        int sb = ks * 32 + ((l >> 4) * 8);
        uint16_t v[8];
        #pragma unroll
        for (int j = 0; j < 8; ++j)
            v[j] = ldb16(tw, g * 2048 + (sb + j) * 32 + t, bf);
        uint4 o;
        o.x = (uint32_t)v[0] | ((uint32_t)v[1] << 16);
        o.y = (uint32_t)v[2] | ((uint32_t)v[3] << 16);
        o.z = (uint32_t)v[4] | ((uint32_t)v[5] << 16);
        o.w = (uint32_t)v[6] | ((uint32_t)v[7] << 16);
        ((uint4*)bt)[it] = o;
    } else if (i < 12192) {                // main bias [544]
        int n = i - 11648;
        bm[n] = (n < 512) ? ldw(eb, n, bf) : (n < 536 ? ldw(gb, n - 512, bf) : 0.0f);
    } else if (i < 12288) {                // tower bias [96]
        int n = i - 12192; tb2[n] = ldw(tb, n, bf);
    } else if (i < 12480) {                // out w [192]
        int n = i - 12288; owf[n] = ldw(ow, n, bf);
    } else if (i < 12486) {                // out b [6]
        int n = i - 12480; obf[n] = ldw(ob, n, bf);
    }
}

// ---------------------------------------------------------------------------
// Kernel 1: embedding gather + sum over L. 2 threads per (f,b): thread h
// sums dims h*8..h*8+7 (16B per row) with 20 fully-unrolled independent loads.
// ---------------------------------------------------------------------------
__global__ __launch_bounds__(256) void gather_sum(
    const void* __restrict__ ids_raw,
    const void* __restrict__ emb_raw,
    uint16_t* __restrict__ xout,
    const int* __restrict__ flags)
{
    const bool i64 = flags[0] != 0;
    const bool bf  = flags[1] != 0;
    int tid = blockIdx.x * 256 + threadIdx.x;   // 0..327679 (exact grid 1280 blocks)
    int h    = tid & 1;
    int pair = tid >> 1;
    int f = pair >> 14;
    int b = pair & (BATCH - 1);

    int idv[NIDS];
    if (i64) {
        const int4* p4 = (const int4*)((const long long*)ids_raw +
                                       ((size_t)f * BATCH + b) * NIDS);
        #pragma unroll
        for (int j = 0; j < NIDS / 2; ++j) {
            int4 q = p4[j];
            idv[2 * j + 0] = q.x;
            idv[2 * j + 1] = q.z;
        }
    } else {
        const int4* p4 = (const int4*)((const int*)ids_raw +
                                       ((size_t)f * BATCH + b) * NIDS);
        #pragma unroll
        for (int j = 0; j < NIDS / 4; ++j) {
            int4 q = p4[j];
            idv[4 * j + 0] = q.x; idv[4 * j + 1] = q.y;
            idv[4 * j + 2] = q.z; idv[4 * j + 3] = q.w;
        }
    }

    float acc[8];
    #pragma unroll
    for (int d = 0; d < 8; ++d) acc[d] = 0.0f;

    if (bf) {
        #pragma unroll
        for (int l = 0; l < NIDS; ++l) {
            uint4 r = *(const uint4*)((const uint16_t*)emb_raw +
                                      (size_t)idv[l] * DEMB + h * 8);
            acc[0] += bflo(r.x); acc[1] += bfhi(r.x);
            acc[2] += bflo(r.y); acc[3] += bfhi(r.y);
            acc[4] += bflo(r.z); acc[5] += bfhi(r.z);
            acc[6] += bflo(r.w); acc[7] += bfhi(r.w);
        }
    } else {
        #pragma unroll
        for (int l = 0; l < NIDS; ++l) {
            const float4* p = (const float4*)((const float*)emb_raw +
                                              (size_t)idv[l] * DEMB + h * 8);
            float4 r0 = p[0], r1 = p[1];
            acc[0] += r0.x; acc[1] += r0.y; acc[2] += r0.z; acc[3] += r0.w;
            acc[4] += r1.x; acc[5] += r1.y; acc[6] += r1.z; acc[7] += r1.w;
        }
    }

    uint4 o;
    o.x = (uint32_t)f2bf(acc[0]) | ((uint32_t)f2bf(acc[1]) << 16);
    o.y = (uint32_t)f2bf(acc[2]) | ((uint32_t)f2bf(acc[3]) << 16);
    o.z = (uint32_t)f2bf(acc[4]) | ((uint32_t)f2bf(acc[5]) << 16);
    o.w = (uint32_t)f2bf(acc[6]) | ((uint32_t)f2bf(acc[7]) << 16);
    *(uint4*)(xout + (size_t)b * NFEAT + f * DEMB + h * 8) = o;
}

// ---------------------------------------------------------------------------
// Kernel 2: MFMA MMoE + towers + ESMM head (verified in R5; checkers removed).
// 32 samples/block, 4 waves. Output dtype per flags[1].
// ---------------------------------------------------------------------------
__global__ __launch_bounds__(256) void moe_fwd(
    const uint16_t* __restrict__ xbf,
    const uint16_t* __restrict__ bp,   // main B-pack
    const float*    __restrict__ bm,   // main bias [544] fp32
    const uint16_t* __restrict__ btw,  // tower B-pack
    const float*    __restrict__ btb,  // tower bias [96] fp32
    const float*    __restrict__ owf,  // out w [192] fp32
    const float*    __restrict__ obf,  // out b [6] fp32
    const int* __restrict__ flags,
    void* __restrict__ out)
{
    __shared__ uint16_t exp_lds[32][520];   // 33,280 B
    __shared__ float    gate_lds[32][33];   //  4,224 B
    __shared__ uint16_t mix_lds[32][200];   // 12,800 B
    __shared__ float    tow_lds[32][100];   // 12,800 B
    __shared__ float    prob_lds[32][6];    //    768 B  -> 63,872 B

    const bool bfw = flags[1] != 0;
    const int tid = threadIdx.x;
    const int w = tid >> 6, l = tid & 63;
    const int lm = l & 15, q = l >> 4;
    const int b0 = blockIdx.x * 32;
    const int mrow = (w & 1) * 16;
    const int nhalf = w >> 1;

    // ---- A fragments: rows b0+mrow+lm, all 5 K-steps, held in registers ----
    bfrag a[5];
    {
        const uint16_t* xr = xbf + (size_t)(b0 + mrow + lm) * NFEAT + q * 8;
        #pragma unroll
        for (int ks = 0; ks < 5; ++ks)
            a[ks] = *(const bfrag*)(xr + ks * 32);
    }

    // ---- expert + gate MFMA GEMM: 17 N-tiles per wave ----
    const int nt0 = nhalf * 17;
    for (int it = 0; it < 17; ++it) {
        int nt = nt0 + it;
        f32x4 acc = {0.0f, 0.0f, 0.0f, 0.0f};
        const bfrag* bpp = (const bfrag*)bp + (size_t)(nt * 5) * 64 + l;
        #pragma unroll
        for (int ks = 0; ks < 5; ++ks) {
            bfrag b = bpp[ks * 64];
            acc = __builtin_amdgcn_mfma_f32_16x16x32_bf16(a[ks], b, acc, 0, 0, 0);
        }
        int col = nt * 16 + lm;
        float bias = bm[col];
        if (col < 512) {
            #pragma unroll
            for (int r = 0; r < 4; ++r)
                exp_lds[mrow + q * 4 + r][col] = f2bf(fmaxf(acc[r] + bias, 0.0f));
        } else {
            #pragma unroll
            for (int r = 0; r < 4; ++r)
                gate_lds[mrow + q * 4 + r][col - 512] = acc[r] + bias;
        }
    }
    __syncthreads();

    const int sm = tid >> 3, j = tid & 7;   // 32 samples x 8 threads

    // ---- gate softmax (j<3 -> g=j) ----
    if (j < 3) {
        float* gl = &gate_lds[sm][j * 8];
        float m = gl[0];
        #pragma unroll
        for (int e = 1; e < 8; ++e) m = fmaxf(m, gl[e]);
        float ex[8], s = 0.0f;
        #pragma unroll
        for (int e = 0; e < 8; ++e) { ex[e] = __expf(gl[e] - m); s += ex[e]; }
        float inv = 1.0f / s;
        #pragma unroll
        for (int e = 0; e < 8; ++e) gl[e] = ex[e] * inv;
    }
    __syncthreads();

    // ---- mix[g][s]: thread j does s = j*8..j*8+7 for all g; bf16 out ----
    for (int g = 0; g < NG; ++g) {
        float m8[8];
        #pragma unroll
        for (int i = 0; i < 8; ++i) m8[i] = 0.0f;
        #pragma unroll
        for (int e = 0; e < NEXP; ++e) {
            float gv = gate_lds[sm][g * 8 + e];
            uint4 u = *(const uint4*)&exp_lds[sm][e * 64 + j * 8];
            m8[0] = fmaf(gv, bflo(u.x), m8[0]); m8[1] = fmaf(gv, bfhi(u.x), m8[1]);
            m8[2] = fmaf(gv, bflo(u.y), m8[2]); m8[3] = fmaf(gv, bfhi(u.y), m8[3]);
            m8[4] = fmaf(gv, bflo(u.z), m8[4]); m8[5] = fmaf(gv, bfhi(u.z), m8[5]);
            m8[6] = fmaf(gv, bflo(u.w), m8[6]); m8[7] = fmaf(gv, bfhi(u.w), m8[7]);
        }
        uint4 o;
        o.x = (uint32_t)f2bf(m8[0]) | ((uint32_t)f2bf(m8[1]) << 16);
        o.y = (uint32_t)f2bf(m8[2]) | ((uint32_t)f2bf(m8[3]) << 16);
        o.z = (uint32_t)f2bf(m8[4]) | ((uint32_t)f2bf(m8[5]) << 16);
        o.w = (uint32_t)f2bf(m8[6]) | ((uint32_t)f2bf(m8[7]) << 16);
        *(uint4*)&mix_lds[sm][g * 64 + j * 8] = o;
    }
    __syncthreads();

    // ---- tower MFMA: 12 units (3g x 2mt x 2nt), wave w does u = w, w+4, w+8 ----
    for (int u = w; u < 12; u += 4) {
        int g = u >> 2, mt = (u >> 1) & 1, ntile = u & 1;
        f32x4 acc = {0.0f, 0.0f, 0.0f, 0.0f};
        #pragma unroll
        for (int ks = 0; ks < 2; ++ks) {
            bfrag av = *(const bfrag*)&mix_lds[mt * 16 + lm][g * 64 + ks * 32 + q * 8];
            bfrag bv = *(const bfrag*)(btw + (size_t)((((g * 2 + ntile) * 2 + ks) * 64 + l)) * 8);
            acc = __builtin_amdgcn_mfma_f32_16x16x32_bf16(av, bv, acc, 0, 0, 0);
        }
        int t = ntile * 16 + lm;
        float bias = btb[g * 32 + t];
        #pragma unroll
        for (int r = 0; r < 4; ++r)
            tow_lds[mt * 16 + q * 4 + r][g * 32 + t] = fmaxf(acc[r] + bias, 0.0f);
    }
    __syncthreads();

    // ---- out head: j<3 -> g=j: 2 logits, softmax, clip ----
    if (j < 3) {
        int g = j;
        float l0 = obf[2 * g], l1 = obf[2 * g + 1];
        #pragma unroll 8
        for (int t = 0; t < NT; ++t) {
            float tv = tow_lds[sm][g * 32 + t];
            l0 = fmaf(tv, owf[g * 64 + 2 * t], l0);
            l1 = fmaf(tv, owf[g * 64 + 2 * t + 1], l1);
        }
        float m  = fmaxf(l0, l1);
        float e0 = __expf(l0 - m);
        float e1 = __expf(l1 - m);
        float inv = 1.0f / (e0 + e1);
        float p0 = fminf(fmaxf(e0 * inv, 1e-15f), 1.0f);
        float p1 = fminf(fmaxf(e1 * inv, 1e-15f), 1.0f);
        prob_lds[sm][2 * g + 0] = p0;
        prob_lds[sm][2 * g + 1] = p1;
    }
    __syncthreads();

    // ---- assemble 10 outputs per sample, dtype per flags[1] ----
    {
        float ctr0 = prob_lds[sm][0], ctr1 = prob_lds[sm][1];
        float cvr0 = prob_lds[sm][2], cvr1 = prob_lds[sm][3];
        float imp1 = prob_lds[sm][5];
        float ctcvr1 = ctr1 * cvr1;
        for (int o = j; o < 10; o += 8) {
            float v;
            switch (o) {
                case 0: v = ctr0; break;
                case 1: v = ctr1; break;
                case 2: v = ctr1; break;
                case 3: v = cvr0; break;
                case 4: v = cvr1; break;
                case 5: v = cvr1; break;
                case 6: v = 1.0f - ctcvr1; break;
                case 7: v = ctcvr1; break;
                case 8: v = ctcvr1; break;
                default: v = imp1; break;
            }
            if (bfw) ((uint16_t*)out)[(size_t)(b0 + sm) * 10 + o] = f2bf(v);
            else     ((float*)out)[(size_t)(b0 + sm) * 10 + o]    = v;
        }
    }
}

// ---------------------------------------------------------------------------
extern "C" void kernel_launch(void* const* d_in, const int* in_sizes, int n_in,
                              void* d_out, int out_size, void* d_ws, size_t ws_size,
                              hipStream_t stream) {
    const void* ids = d_in[0];
    const void* emb = d_in[1];

    char* ws = (char*)d_ws;
    uint16_t* xbf = (uint16_t*)ws;
    uint16_t* bpk = (uint16_t*)(ws + BP_OFF_B);
    float*    bm  = (float*)(ws + BM_OFF_B);
    uint16_t* btw = (uint16_t*)(ws + BT_OFF_B);
    float*    tb2 = (float*)(ws + TB2_OFF_B);
    float*    owf = (float*)(ws + OWF_OFF_B);
    float*    obf = (float*)(ws + OBF_OFF_B);
    int*    flags = (int*)(ws + FLG_OFF_B);

    sniff_dtypes<<<1, 64, 0, stream>>>((const uint32_t*)ids, (const uint32_t*)emb, flags);
    pack_weights<<<49, 256, 0, stream>>>(
        d_in[2], d_in[3], d_in[4], d_in[5], d_in[6], d_in[7], d_in[8], d_in[9],
        bpk, bm, btw, tb2, owf, obf, flags);
    gather_sum<<<(NFIELD * BATCH * 2) / 256, 256, 0, stream>>>(ids, emb, xbf, flags);
    moe_fwd<<<BATCH / 32, 256, 0, stream>>>(
        xbf, bpk, bm, btw, tb2, owf, obf, flags, d_out);
}

// Round 7
// 177.030 us; speedup vs baseline: 2.1123x; 1.1575x over previous
//
#include <hip/hip_runtime.h>
#include <hip/hip_bf16.h>
#include <cstdint>
#include <cstddef>

// Problem constants
#define NFIELD 10
#define BATCH  16384
#define NIDS   20
#define DEMB   16
#define NFEAT  160   // NFIELD * DEMB
#define NEXP   8
#define NS     64
#define NG     3
#define NT     32

// workspace layout (bytes), all regions 16B-aligned
#define BP_OFF_B  0                                // main B-pack: 34*5*64*8*2 = 174,080
#define BM_OFF_B  (BP_OFF_B + 174080)              // main bias fp32[544] = 2,176
#define BT_OFF_B  (BM_OFF_B + 2176)                // tower B-pack: 3*2*2*64*8*2 = 12,288
#define TB2_OFF_B (BT_OFF_B + 12288)               // tower bias fp32[96] = 384
#define OWF_OFF_B (TB2_OFF_B + 384)                // out w fp32[192] = 768
#define OBF_OFF_B (OWF_OFF_B + 768)                // out b fp32[6]

typedef short bfrag __attribute__((ext_vector_type(8)));  // 8 bf16 (4 VGPRs)
typedef float f32x4 __attribute__((ext_vector_type(4)));

__device__ __forceinline__ float bflo(uint32_t u) {
    union { uint32_t u; float f; } c; c.u = u << 16; return c.f;
}
__device__ __forceinline__ float bfhi(uint32_t u) {
    union { uint32_t u; float f; } c; c.u = u & 0xffff0000u; return c.f;
}
__device__ __forceinline__ float bf1(uint16_t v) {
    union { uint32_t u; float f; } c; c.u = ((uint32_t)v) << 16; return c.f;
}
__device__ __forceinline__ uint16_t f2bf(float f) {
    union { float f; uint32_t u; } c; c.f = f;
    uint32_t r = c.u + 0x7fffu + ((c.u >> 16) & 1u);  // RTNE
    return (uint16_t)(r >> 16);
}
__device__ __forceinline__ float ldw(const void* p, int i, bool bf) {
    return bf ? bf1(((const uint16_t*)p)[i]) : ((const float*)p)[i];
}
__device__ __forceinline__ uint16_t ldb16(const void* p, int i, bool bf) {
    return bf ? ((const uint16_t*)p)[i] : f2bf(((const float*)p)[i]);
}
// per-block emb-dtype sniff (thread 0 must call; result via shared)
__device__ __forceinline__ int sniff_bf(const uint32_t* emb_w) {
    int n_bf = 0;
    #pragma unroll
    for (int t = 0; t < 16; ++t) {
        uint32_t wv = emb_w[(size_t)t * 500000];   // <= 30 MB, in-bounds both ways
        uint32_t v = (wv >> 8) & 0x7Fu;
        n_bf += (v >= 0x3Bu && v <= 0x3Fu);
    }
    return n_bf >= 8;
}

// ---------------------------------------------------------------------------
// Kernel P: pack weights (either dtype) into MFMA B-frag bf16 + fp32 biases.
// Main GEMM Wc[k=160][n=544]: n<512 -> expert_w[n>>6][k][n&63];
//   512<=n<536 -> gate_w[(n-512)>>3][k][(n-512)&7]; else 0.
// Frag: [(nt*5+ks)*64+lane]*8+j, element = Wc[ks*32+(lane>>4)*8+j][nt*16+(lane&15)]
// ---------------------------------------------------------------------------
__global__ __launch_bounds__(256) void pack_weights(
    const uint32_t* __restrict__ emb_w,
    const void* __restrict__ ew, const void* __restrict__ eb,
    const void* __restrict__ gw, const void* __restrict__ gb,
    const void* __restrict__ tw, const void* __restrict__ tb,
    const void* __restrict__ ow, const void* __restrict__ ob,
    uint16_t* __restrict__ bp, float* __restrict__ bm,
    uint16_t* __restrict__ bt, float* __restrict__ tb2,
    float* __restrict__ owf, float* __restrict__ obf)
{
    __shared__ int sbf;
    if (threadIdx.x == 0) sbf = sniff_bf(emb_w);
    __syncthreads();
    const bool bf = sbf != 0;

    int i = blockIdx.x * 256 + threadIdx.x;
    if (i < 10880) {                       // main B-pack: 34 tiles * 5 ksteps * 64 lanes
        int nt = i / 320, rem = i % 320;
        int ks = rem / 64, l = rem % 64;
        int n  = nt * 16 + (l & 15);
        int kb = ks * 32 + ((l >> 4) * 8);
        uint16_t v[8];
        #pragma unroll
        for (int j = 0; j < 8; ++j) {
            int k = kb + j;
            uint16_t x;
            if (n < 512)      x = ldb16(ew, (n >> 6) * 10240 + k * 64 + (n & 63), bf);
            else if (n < 536) x = ldb16(gw, ((n - 512) >> 3) * 1280 + k * 8 + ((n - 512) & 7), bf);
            else              x = 0;
            v[j] = x;
        }
        uint4 o;
        o.x = (uint32_t)v[0] | ((uint32_t)v[1] << 16);
        o.y = (uint32_t)v[2] | ((uint32_t)v[3] << 16);
        o.z = (uint32_t)v[4] | ((uint32_t)v[5] << 16);
        o.w = (uint32_t)v[6] | ((uint32_t)v[7] << 16);
        ((uint4*)bp)[i] = o;
    } else if (i < 11648) {                // tower B-pack: 3g * 2nt * 2ks * 64 lanes
        int it = i - 10880;
        int g = it / 256, rem = it % 256;
        int ntile = rem / 128, ks = (rem / 64) & 1, l = rem % 64;
        int t  = ntile * 16 + (l & 15);
        int sb = ks * 32 + ((l >> 4) * 8);
        uint16_t v[8];
        #pragma unroll
        for (int j = 0; j < 8; ++j)
            v[j] = ldb16(tw, g * 2048 + (sb + j) * 32 + t, bf);
        uint4 o;
        o.x = (uint32_t)v[0] | ((uint32_t)v[1] << 16);
        o.y = (uint32_t)v[2] | ((uint32_t)v[3] << 16);
        o.z = (uint32_t)v[4] | ((uint32_t)v[5] << 16);
        o.w = (uint32_t)v[6] | ((uint32_t)v[7] << 16);
        ((uint4*)bt)[it] = o;
    } else if (i < 12192) {                // main bias [544]
        int n = i - 11648;
        bm[n] = (n < 512) ? ldw(eb, n, bf) : (n < 536 ? ldw(gb, n - 512, bf) : 0.0f);
    } else if (i < 12288) {                // tower bias [96]
        int n = i - 12192; tb2[n] = ldw(tb, n, bf);
    } else if (i < 12480) {                // out w [192]
        int n = i - 12288; owf[n] = ldw(ow, n, bf);
    } else if (i < 12486) {                // out b [6]
        int n = i - 12480; obf[n] = ldw(ob, n, bf);
    }
}

// ---------------------------------------------------------------------------
// Kernel F: FUSED gather + MFMA MMoE + towers + ESMM head.
// 32 samples/block, 512 blocks. Gather stages x into LDS scratch (overlaid
// on exp_lds); MFMA of other blocks overlaps this block's gather traffic.
// ---------------------------------------------------------------------------
__global__ __launch_bounds__(256, 2) void moe_fused(
    const void* __restrict__ ids_raw,
    const void* __restrict__ emb_raw,
    const uint16_t* __restrict__ bp,   // main B-pack
    const float*    __restrict__ bm,   // main bias [544] fp32
    const uint16_t* __restrict__ btw,  // tower B-pack
    const float*    __restrict__ btb,  // tower bias [96] fp32
    const float*    __restrict__ owf,  // out w [192] fp32
    const float*    __restrict__ obf,  // out b [6] fp32
    void* __restrict__ out)
{
    __shared__ uint16_t exp_lds[32][520];   // 33,280 B (first 10.8 KB double as x scratch)
    __shared__ float    gate_lds[32][33];   //  4,224 B
    __shared__ uint16_t mix_lds[32][200];   // 12,800 B
    __shared__ float    tow_lds[32][100];   // 12,800 B
    __shared__ float    prob_lds[32][6];    //    768 B
    __shared__ int      sflags;             // bit0 = ids int64, bit1 = floats bf16

    const int tid = threadIdx.x;
    const int w = tid >> 6, l = tid & 63;
    const int lm = l & 15, q = l >> 4;
    const int b0 = blockIdx.x * 32;
    const int mrow = (w & 1) * 16;
    const int nhalf = w >> 1;

    // ---- per-block dtype sniff (thread 0) ----
    if (tid == 0) {
        int n_hi = 0;
        #pragma unroll
        for (int t = 0; t < 16; ++t) {
            size_t p = (size_t)t * 100000;  // pair idx <= 1.5M: in-bounds both ways
            n_hi += (((const uint32_t*)ids_raw)[2 * p + 1] != 0);
        }
        sflags = ((n_hi < 2) ? 1 : 0) | (sniff_bf((const uint32_t*)emb_raw) ? 2 : 0);
    }
    __syncthreads();
    const bool i64 = (sflags & 1) != 0;
    const bool bfe = (sflags & 2) != 0;

    // ---- Phase 0: gather x[32][160] (bf16) into LDS scratch, stride 168 ----
    uint16_t* xs = &exp_lds[0][0];
    for (int p = tid; p < 32 * NFIELD; p += 256) {
        int f = p >> 5, s = p & 31;
        int idv[NIDS];
        if (i64) {
            const int4* p4 = (const int4*)((const long long*)ids_raw +
                                           ((size_t)f * BATCH + (b0 + s)) * NIDS);
            #pragma unroll
            for (int j = 0; j < NIDS / 2; ++j) {
                int4 t4 = p4[j];
                idv[2 * j + 0] = t4.x;
                idv[2 * j + 1] = t4.z;
            }
        } else {
            const int4* p4 = (const int4*)((const int*)ids_raw +
                                           ((size_t)f * BATCH + (b0 + s)) * NIDS);
            #pragma unroll
            for (int j = 0; j < NIDS / 4; ++j) {
                int4 t4 = p4[j];
                idv[4 * j + 0] = t4.x; idv[4 * j + 1] = t4.y;
                idv[4 * j + 2] = t4.z; idv[4 * j + 3] = t4.w;
            }
        }

        float acc[16];
        #pragma unroll
        for (int d = 0; d < 16; ++d) acc[d] = 0.0f;

        if (bfe) {
            #pragma unroll 5
            for (int ll = 0; ll < NIDS; ++ll) {
                const uint4* row = (const uint4*)((const uint16_t*)emb_raw +
                                                  (size_t)idv[ll] * DEMB);
                uint4 r0 = row[0];
                uint4 r1 = row[1];
                acc[0]  += bflo(r0.x); acc[1]  += bfhi(r0.x);
                acc[2]  += bflo(r0.y); acc[3]  += bfhi(r0.y);
                acc[4]  += bflo(r0.z); acc[5]  += bfhi(r0.z);
                acc[6]  += bflo(r0.w); acc[7]  += bfhi(r0.w);
                acc[8]  += bflo(r1.x); acc[9]  += bfhi(r1.x);
                acc[10] += bflo(r1.y); acc[11] += bfhi(r1.y);
                acc[12] += bflo(r1.z); acc[13] += bfhi(r1.z);
                acc[14] += bflo(r1.w); acc[15] += bfhi(r1.w);
            }
        } else {
            #pragma unroll 5
            for (int ll = 0; ll < NIDS; ++ll) {
                const float4* row = (const float4*)((const float*)emb_raw +
                                                    (size_t)idv[ll] * DEMB);
                float4 r0 = row[0], r1 = row[1], r2 = row[2], r3 = row[3];
                acc[0]  += r0.x; acc[1]  += r0.y; acc[2]  += r0.z; acc[3]  += r0.w;
                acc[4]  += r1.x; acc[5]  += r1.y; acc[6]  += r1.z; acc[7]  += r1.w;
                acc[8]  += r2.x; acc[9]  += r2.y; acc[10] += r2.z; acc[11] += r2.w;
                acc[12] += r3.x; acc[13] += r3.y; acc[14] += r3.z; acc[15] += r3.w;
            }
        }

        uint32_t pk[8];
        #pragma unroll
        for (int j = 0; j < 8; ++j)
            pk[j] = (uint32_t)f2bf(acc[2 * j]) | ((uint32_t)f2bf(acc[2 * j + 1]) << 16);
        uint4* dst = (uint4*)(xs + (size_t)s * 168 + f * DEMB);
        dst[0] = make_uint4(pk[0], pk[1], pk[2], pk[3]);
        dst[1] = make_uint4(pk[4], pk[5], pk[6], pk[7]);
    }
    __syncthreads();

    // ---- Phase 1: A fragments from LDS scratch into registers ----
    bfrag a[5];
    #pragma unroll
    for (int ks = 0; ks < 5; ++ks)
        a[ks] = *(const bfrag*)(xs + (size_t)(mrow + lm) * 168 + ks * 32 + q * 8);
    __syncthreads();   // all reads done before GEMM overwrites the scratch

    // ---- Phase 2: expert + gate MFMA GEMM: 17 N-tiles per wave ----
    const int nt0 = nhalf * 17;
    for (int it = 0; it < 17; ++it) {
        int nt = nt0 + it;
        f32x4 acc = {0.0f, 0.0f, 0.0f, 0.0f};
        const bfrag* bpp = (const bfrag*)bp + (size_t)(nt * 5) * 64 + l;
        #pragma unroll
        for (int ks = 0; ks < 5; ++ks) {
            bfrag b = bpp[ks * 64];
            acc = __builtin_amdgcn_mfma_f32_16x16x32_bf16(a[ks], b, acc, 0, 0, 0);
        }
        int col = nt * 16 + lm;
        float bias = bm[col];
        if (col < 512) {
            #pragma unroll
            for (int r = 0; r < 4; ++r)
                exp_lds[mrow + q * 4 + r][col] = f2bf(fmaxf(acc[r] + bias, 0.0f));
        } else {
            #pragma unroll
            for (int r = 0; r < 4; ++r)
                gate_lds[mrow + q * 4 + r][col - 512] = acc[r] + bias;
        }
    }
    __syncthreads();

    const int sm = tid >> 3, j = tid & 7;   // 32 samples x 8 threads

    // ---- gate softmax (j<3 -> g=j) ----
    if (j < 3) {
        float* gl = &gate_lds[sm][j * 8];
        float m = gl[0];
        #pragma unroll
        for (int e = 1; e < 8; ++e) m = fmaxf(m, gl[e]);
        float ex[8], s = 0.0f;
        #pragma unroll
        for (int e = 0; e < 8; ++e) { ex[e] = __expf(gl[e] - m); s += ex[e]; }
        float inv = 1.0f / s;
        #pragma unroll
        for (int e = 0; e < 8; ++e) gl[e] = ex[e] * inv;
    }
    __syncthreads();

    // ---- mix[g][s]: thread j does s = j*8..j*8+7 for all g; bf16 out ----
    for (int g = 0; g < NG; ++g) {
        float m8[8];
        #pragma unroll
        for (int i = 0; i < 8; ++i) m8[i] = 0.0f;
        #pragma unroll
        for (int e = 0; e < NEXP; ++e) {
            float gv = gate_lds[sm][g * 8 + e];
            uint4 u = *(const uint4*)&exp_lds[sm][e * 64 + j * 8];
            m8[0] = fmaf(gv, bflo(u.x), m8[0]); m8[1] = fmaf(gv, bfhi(u.x), m8[1]);
            m8[2] = fmaf(gv, bflo(u.y), m8[2]); m8[3] = fmaf(gv, bfhi(u.y), m8[3]);
            m8[4] = fmaf(gv, bflo(u.z), m8[4]); m8[5] = fmaf(gv, bfhi(u.z), m8[5]);
            m8[6] = fmaf(gv, bflo(u.w), m8[6]); m8[7] = fmaf(gv, bfhi(u.w), m8[7]);
        }
        uint4 o;
        o.x = (uint32_t)f2bf(m8[0]) | ((uint32_t)f2bf(m8[1]) << 16);
        o.y = (uint32_t)f2bf(m8[2]) | ((uint32_t)f2bf(m8[3]) << 16);
        o.z = (uint32_t)f2bf(m8[4]) | ((uint32_t)f2bf(m8[5]) << 16);
        o.w = (uint32_t)f2bf(m8[6]) | ((uint32_t)f2bf(m8[7]) << 16);
        *(uint4*)&mix_lds[sm][g * 64 + j * 8] = o;
    }
    __syncthreads();

    // ---- tower MFMA: 12 units (3g x 2mt x 2nt), wave w does u = w, w+4, w+8 ----
    for (int u = w; u < 12; u += 4) {
        int g = u >> 2, mt = (u >> 1) & 1, ntile = u & 1;
        f32x4 acc = {0.0f, 0.0f, 0.0f, 0.0f};
        #pragma unroll
        for (int ks = 0; ks < 2; ++ks) {
            bfrag av = *(const bfrag*)&mix_lds[mt * 16 + lm][g * 64 + ks * 32 + q * 8];
            bfrag bv = *(const bfrag*)(btw + (size_t)((((g * 2 + ntile) * 2 + ks) * 64 + l)) * 8);
            acc = __builtin_amdgcn_mfma_f32_16x16x32_bf16(av, bv, acc, 0, 0, 0);
        }
        int t = ntile * 16 + lm;
        float bias = btb[g * 32 + t];
        #pragma unroll
        for (int r = 0; r < 4; ++r)
            tow_lds[mt * 16 + q * 4 + r][g * 32 + t] = fmaxf(acc[r] + bias, 0.0f);
    }
    __syncthreads();

    // ---- out head: j<3 -> g=j: 2 logits, softmax, clip ----
    if (j < 3) {
        int g = j;
        float l0 = obf[2 * g], l1 = obf[2 * g + 1];
        #pragma unroll 8
        for (int t = 0; t < NT; ++t) {
            float tv = tow_lds[sm][g * 32 + t];
            l0 = fmaf(tv, owf[g * 64 + 2 * t], l0);
            l1 = fmaf(tv, owf[g * 64 + 2 * t + 1], l1);
        }
        float m  = fmaxf(l0, l1);
        float e0 = __expf(l0 - m);
        float e1 = __expf(l1 - m);
        float inv = 1.0f / (e0 + e1);
        float p0 = fminf(fmaxf(e0 * inv, 1e-15f), 1.0f);
        float p1 = fminf(fmaxf(e1 * inv, 1e-15f), 1.0f);
        prob_lds[sm][2 * g + 0] = p0;
        prob_lds[sm][2 * g + 1] = p1;
    }
    __syncthreads();

    // ---- assemble 10 outputs per sample, dtype per sniff ----
    {
        float ctr0 = prob_lds[sm][0], ctr1 = prob_lds[sm][1];
        float cvr0 = prob_lds[sm][2], cvr1 = prob_lds[sm][3];
        float imp1 = prob_lds[sm][5];
        float ctcvr1 = ctr1 * cvr1;
        for (int o = j; o < 10; o += 8) {
            float v;
            switch (o) {
                case 0: v = ctr0; break;
                case 1: v = ctr1; break;
                case 2: v = ctr1; break;
                case 3: v = cvr0; break;
                case 4: v = cvr1; break;
                case 5: v = cvr1; break;
                case 6: v = 1.0f - ctcvr1; break;
                case 7: v = ctcvr1; break;
                case 8: v = ctcvr1; break;
                default: v = imp1; break;
            }
            if (bfe) ((uint16_t*)out)[(size_t)(b0 + sm) * 10 + o] = f2bf(v);
            else     ((float*)out)[(size_t)(b0 + sm) * 10 + o]    = v;
        }
    }
}

// ---------------------------------------------------------------------------
extern "C" void kernel_launch(void* const* d_in, const int* in_sizes, int n_in,
                              void* d_out, int out_size, void* d_ws, size_t ws_size,
                              hipStream_t stream) {
    const void* ids = d_in[0];
    const void* emb = d_in[1];

    char* ws = (char*)d_ws;
    uint16_t* bpk = (uint16_t*)(ws + BP_OFF_B);
    float*    bm  = (float*)(ws + BM_OFF_B);
    uint16_t* btw = (uint16_t*)(ws + BT_OFF_B);
    float*    tb2 = (float*)(ws + TB2_OFF_B);
    float*    owf = (float*)(ws + OWF_OFF_B);
    float*    obf = (float*)(ws + OBF_OFF_B);

    pack_weights<<<49, 256, 0, stream>>>(
        (const uint32_t*)emb,
        d_in[2], d_in[3], d_in[4], d_in[5], d_in[6], d_in[7], d_in[8], d_in[9],
        bpk, bm, btw, tb2, owf, obf);
    moe_fused<<<BATCH / 32, 256, 0, stream>>>(
        ids, emb, bpk, bm, btw, tb2, owf, obf, d_out);
}